// Round 4
// baseline (4790.964 us; speedup 1.0000x reference)
//
#include <hip/hip_runtime.h>
#include <stdint.h>

#define B_ 64
#define H_ 1024
#define V_ 32000
#define T_ 20

typedef __attribute__((ext_vector_type(8))) __bf16 bf16x8;
typedef __attribute__((ext_vector_type(4))) float f32x4;
typedef unsigned short u16;
typedef unsigned long long u64;

// ---------------- ws layout (bytes) ----------------
#define OFF_HB0      0x000000u            // h fp32, parity 0   (256 KB)
#define OFF_HB1      0x040000u            // h fp32, parity 1
#define OFF_HHI0     0x080000u            // h bf16-hi plane, parity 0 (128 KB)
#define OFF_HLO0     0x0A0000u
#define OFF_HHI1     0x0C0000u
#define OFF_HLO1     0x0E0000u
#define OFF_XHI      0x100000u            // x = emb[tok] planes (128 KB each)
#define OFF_XLO      0x120000u
#define OFF_LATHI    0x140000u            // latent planes
#define OFF_LATLO    0x160000u
#define OFF_PART     0x180000u            // 500*64*8 = 256000 B
#define OFF_GBUF     0x1C0000u            // 96 * 4096 * 4 = 1572864 B
#define OFF_CTR      0x340000u            // 32 ints (0..15 gates jt, 16 logits)
#define OFF_WOUTHI   0x400000u            // 32000*1024*2 = 65536000
#define OFF_WOUTLO   (OFF_WOUTHI + 65536000u)
#define OFF_WIHHI    (OFF_WOUTLO + 65536000u)   // 3072*1024*2 = 6291456
#define OFF_WIHLO    (OFF_WIHHI + 6291456u)
#define OFF_WHHHI    (OFF_WIHLO + 6291456u)
#define OFF_WHHLO    (OFF_WHHHI + 6291456u)
#define OFF_WPHI     (OFF_WHHLO + 6291456u)     // 1024*1024*2 = 2097152
#define OFF_WPLO     (OFF_WPHI + 2097152u)

// ---------------- helpers ----------------
__device__ __forceinline__ uint32_t ord_of_float(float x) {
    uint32_t u = __float_as_uint(x);
    return (u & 0x80000000u) ? ~u : (u | 0x80000000u);
}

__device__ __forceinline__ u64 shfl_xor_u64(u64 x, int m) {
    return (u64)__shfl_xor((long long)x, m, 64);
}

// round-to-nearest-even fp32 -> bf16 split: f ~= hi + lo (each bf16)
__device__ __forceinline__ void split_bf16(float f, u16* hi, u16* lo) {
    uint32_t u = __float_as_uint(f);
    uint32_t rh = (u + 0x7FFFu + ((u >> 16) & 1u)) >> 16;
    *hi = (u16)rh;
    float fl = f - __uint_as_float(rh << 16);
    uint32_t ul = __float_as_uint(fl);
    uint32_t rl = (ul + 0x7FFFu + ((ul >> 16) & 1u)) >> 16;
    *lo = (u16)rl;
}

#define MFMA(a, b, c) __builtin_amdgcn_mfma_f32_16x16x32_bf16((a), (b), (c), 0, 0, 0)

// Wave computes 64 A-rows x 16 B-rows over K=1024, 3-term split-bf16.
// A planes: [64][1024] bf16.  Bhi/Blo: pointers to THIS lane's B row (+row*1024).
__device__ __forceinline__ void plane_gemm_16n(
    const u16* __restrict__ Ahi, const u16* __restrict__ Alo,
    const u16* __restrict__ Bhi, const u16* __restrict__ Blo,
    int ln, int q, f32x4* acc)
{
    for (int kc = 0; kc < 1024; kc += 64) {
        int k0 = kc + q * 8, k1 = kc + 32 + q * 8;
        bf16x8 bh0 = *(const bf16x8*)(Bhi + k0);
        bf16x8 bh1 = *(const bf16x8*)(Bhi + k1);
        bf16x8 bl0 = *(const bf16x8*)(Blo + k0);
        bf16x8 bl1 = *(const bf16x8*)(Blo + k1);
#pragma unroll
        for (int mt = 0; mt < 4; mt++) {
            const u16* ar = Ahi + (mt * 16 + ln) * 1024;
            const u16* al = Alo + (mt * 16 + ln) * 1024;
            bf16x8 ah0 = *(const bf16x8*)(ar + k0);
            bf16x8 ah1 = *(const bf16x8*)(ar + k1);
            bf16x8 al0 = *(const bf16x8*)(al + k0);
            bf16x8 al1 = *(const bf16x8*)(al + k1);
            acc[mt] = MFMA(ah0, bh0, acc[mt]);
            acc[mt] = MFMA(ah1, bh1, acc[mt]);
            acc[mt] = MFMA(al0, bh0, acc[mt]);
            acc[mt] = MFMA(al1, bh1, acc[mt]);
            acc[mt] = MFMA(ah0, bl0, acc[mt]);
            acc[mt] = MFMA(ah1, bl1, acc[mt]);
        }
    }
}

// ---------------- D0: split all weights to bf16 hi/lo planes ----------------
__global__ __launch_bounds__(256) void k_split(
    const float* __restrict__ Wout, const float* __restrict__ Wih,
    const float* __restrict__ Whh, const float* __restrict__ Wp,
    const float* __restrict__ latent, const float* __restrict__ emb,
    char* __restrict__ ws)
{
    u16* WoutHi = (u16*)(ws + OFF_WOUTHI); u16* WoutLo = (u16*)(ws + OFF_WOUTLO);
    u16* WihHi  = (u16*)(ws + OFF_WIHHI);  u16* WihLo  = (u16*)(ws + OFF_WIHLO);
    u16* WhhHi  = (u16*)(ws + OFF_WHHHI);  u16* WhhLo  = (u16*)(ws + OFF_WHHLO);
    u16* WpHi   = (u16*)(ws + OFF_WPHI);   u16* WpLo   = (u16*)(ws + OFF_WPLO);
    u16* LatHi  = (u16*)(ws + OFF_LATHI);  u16* LatLo  = (u16*)(ws + OFF_LATLO);
    u16* XHi    = (u16*)(ws + OFF_XHI);    u16* XLo    = (u16*)(ws + OFF_XLO);
    int* ctr    = (int*)(ws + OFF_CTR);

    size_t gid = (size_t)blockIdx.x * 256 + threadIdx.x;
    if (gid < 32) ctr[gid] = 0;

    const size_t N0 = 32768000u;            // Wout
    const size_t N1 = N0 + 3145728u;        // Wih
    const size_t N2 = N1 + 3145728u;        // Whh
    const size_t N3 = N2 + 1048576u;        // Wp
    const size_t N4 = N3 + 65536u;          // latent
    const size_t N5 = N4 + 65536u;          // x(t=0) = emb[SOS=0] broadcast
    size_t stride = (size_t)gridDim.x * 256;
    for (size_t i = gid; i < N5; i += stride) {
        float v; u16 *hi, *lo; size_t o;
        if (i < N0)      { o = i;      v = Wout[o];   hi = WoutHi; lo = WoutLo; }
        else if (i < N1) { o = i - N0; v = Wih[o];    hi = WihHi;  lo = WihLo;  }
        else if (i < N2) { o = i - N1; v = Whh[o];    hi = WhhHi;  lo = WhhLo;  }
        else if (i < N3) { o = i - N2; v = Wp[o];     hi = WpHi;   lo = WpLo;   }
        else if (i < N4) { o = i - N3; v = latent[o]; hi = LatHi;  lo = LatLo;  }
        else             { o = i - N4; v = emb[o & 1023]; hi = XHi; lo = XLo;   }
        split_bf16(v, hi + o, lo + o);
    }
}

// ---------------- D1: init hidden h0 = latent @ Wp^T + bp ----------------
__global__ __launch_bounds__(256) void k_init(const float* __restrict__ bp,
                                              char* __restrict__ ws)
{
    int tid = threadIdx.x, lane = tid & 63, wv = tid >> 6;
    int ln = lane & 15, q = lane >> 4;
    const u16* LatHi = (const u16*)(ws + OFF_LATHI);
    const u16* LatLo = (const u16*)(ws + OFF_LATLO);
    int jb = blockIdx.x * 64 + wv * 16;
    const u16* Bhi = (const u16*)(ws + OFF_WPHI) + (size_t)(jb + ln) * 1024;
    const u16* Blo = (const u16*)(ws + OFF_WPLO) + (size_t)(jb + ln) * 1024;
    f32x4 acc[4];
#pragma unroll
    for (int i = 0; i < 4; i++) acc[i] = (f32x4){0.f, 0.f, 0.f, 0.f};
    plane_gemm_16n(LatHi, LatLo, Bhi, Blo, ln, q, acc);

    float* h0 = (float*)(ws + OFF_HB0);
    u16* hHi = (u16*)(ws + OFF_HHI0);
    u16* hLo = (u16*)(ws + OFF_HLO0);
    int j = jb + ln;
    float b0 = bp[j];
#pragma unroll
    for (int mt = 0; mt < 4; mt++)
#pragma unroll
        for (int r = 0; r < 4; r++) {
            int b = mt * 16 + q * 4 + r;
            float h = acc[mt][r] + b0;
            h0[b * H_ + j] = h;
            split_bf16(h, hHi + b * H_ + j, hLo + b * H_ + j);
        }
}

// ---------------- per-step A: gates GEMM + (last block) GRU elementwise ----
// Grid 32: jt = bx>>1 (output j-tile), half = bx&1 (0: x@Wih^T, 1: h@Whh^T).
__global__ __launch_bounds__(256) void k_gates(
    const float* __restrict__ bih, const float* __restrict__ bhh,
    const u16* __restrict__ xHi, const u16* __restrict__ xLo,
    const u16* __restrict__ hpHi, const u16* __restrict__ hpLo,
    const float* __restrict__ hprev, float* __restrict__ hnext,
    u16* __restrict__ hnHi, u16* __restrict__ hnLo,
    char* __restrict__ ws)
{
    __shared__ int isLast;
    int tid = threadIdx.x, lane = tid & 63, wv = tid >> 6;
    int ln = lane & 15, q = lane >> 4;
    int jt = blockIdx.x >> 1, half = blockIdx.x & 1;

    const u16* Ahi = half ? hpHi : xHi;
    const u16* Alo = half ? hpLo : xLo;
    const u16* WHi = (const u16*)(ws + (half ? OFF_WHHHI : OFF_WIHHI));
    const u16* WLo = (const u16*)(ws + (half ? OFF_WHHLO : OFF_WIHLO));
    float* gbuf = (float*)(ws + OFF_GBUF);
    int* ctr = (int*)(ws + OFF_CTR);

    int jl = wv * 16 + ln;                 // local j within tile (0..63)
    const u16* Bh[3]; const u16* Bl[3];
#pragma unroll
    for (int g = 0; g < 3; g++) {
        size_t row = (size_t)(g * 1024 + jt * 64 + jl) * 1024;
        Bh[g] = WHi + row; Bl[g] = WLo + row;
    }

    f32x4 acc[3][4];
#pragma unroll
    for (int g = 0; g < 3; g++)
#pragma unroll
        for (int i = 0; i < 4; i++) acc[g][i] = (f32x4){0.f, 0.f, 0.f, 0.f};

    for (int kc = 0; kc < 1024; kc += 64) {
        int k0 = kc + q * 8, k1 = kc + 32 + q * 8;
        bf16x8 bh0[3], bh1[3], bl0[3], bl1[3];
#pragma unroll
        for (int g = 0; g < 3; g++) {
            bh0[g] = *(const bf16x8*)(Bh[g] + k0);
            bh1[g] = *(const bf16x8*)(Bh[g] + k1);
            bl0[g] = *(const bf16x8*)(Bl[g] + k0);
            bl1[g] = *(const bf16x8*)(Bl[g] + k1);
        }
#pragma unroll
        for (int mt = 0; mt < 4; mt++) {
            const u16* ar = Ahi + (mt * 16 + ln) * 1024;
            const u16* al = Alo + (mt * 16 + ln) * 1024;
            bf16x8 ah0 = *(const bf16x8*)(ar + k0);
            bf16x8 ah1 = *(const bf16x8*)(ar + k1);
            bf16x8 aL0 = *(const bf16x8*)(al + k0);
            bf16x8 aL1 = *(const bf16x8*)(al + k1);
#pragma unroll
            for (int g = 0; g < 3; g++) {
                acc[g][mt] = MFMA(ah0, bh0[g], acc[g][mt]);
                acc[g][mt] = MFMA(ah1, bh1[g], acc[g][mt]);
                acc[g][mt] = MFMA(aL0, bh0[g], acc[g][mt]);
                acc[g][mt] = MFMA(aL1, bh1[g], acc[g][mt]);
                acc[g][mt] = MFMA(ah0, bl0[g], acc[g][mt]);
                acc[g][mt] = MFMA(ah1, bl1[g], acc[g][mt]);
            }
        }
    }

    // store partials: gbuf[((jt*2+half)*3+g)*4096 + b*64 + jl]
#pragma unroll
    for (int g = 0; g < 3; g++) {
        float* og = gbuf + (size_t)((jt * 2 + half) * 3 + g) * 4096;
#pragma unroll
        for (int mt = 0; mt < 4; mt++)
#pragma unroll
            for (int r = 0; r < 4; r++) {
                int b = mt * 16 + q * 4 + r;
                og[b * 64 + jl] = acc[g][mt][r];
            }
    }
    __syncthreads();                     // drain block's stores (vmcnt before barrier)
    if (tid == 0) {
        __threadfence();                 // release: publish gbuf
        int old = atomicAdd(&ctr[jt], 1);
        isLast = (old == 1);
    }
    __syncthreads();
    if (isLast) {
        if (tid == 0) __threadfence();   // acquire: see sibling's gbuf
        __syncthreads();
        const float* gi = gbuf + (size_t)((jt * 2 + 0) * 3) * 4096;
        const float* gh = gbuf + (size_t)((jt * 2 + 1) * 3) * 4096;
        for (int i = tid; i < 4096; i += 256) {
            int b = i >> 6, jj = i & 63;
            int j = jt * 64 + jj;
            float ir = gi[i]            + bih[j];
            float iz = gi[4096 + i]     + bih[H_ + j];
            float in_ = gi[2 * 4096 + i] + bih[2 * H_ + j];
            float hr = gh[i]            + bhh[j];
            float hz = gh[4096 + i]     + bhh[H_ + j];
            float hn = gh[2 * 4096 + i] + bhh[2 * H_ + j];
            float r = 1.f / (1.f + expf(-(ir + hr)));
            float z = 1.f / (1.f + expf(-(iz + hz)));
            float n = tanhf(in_ + r * hn);
            float h = (1.f - z) * n + z * hprev[b * H_ + j];
            hnext[b * H_ + j] = h;
            split_bf16(h, hnHi + b * H_ + j, hnLo + b * H_ + j);
        }
        if (tid == 0) ctr[jt] = 0;       // visible to next step via dispatch boundary
    }
}

// ---------------- per-step B: logits + argmax + (last block) token + x ----
__global__ __launch_bounds__(256) void k_logits(
    const u16* __restrict__ hHi, const u16* __restrict__ hLo,
    const float* __restrict__ bout, const float* __restrict__ emb,
    float* __restrict__ out, int t, int doX, char* __restrict__ ws)
{
    __shared__ u64 redLds[64];
    __shared__ int tokLds[64];
    __shared__ int isLast;
    int tid = threadIdx.x, lane = tid & 63, wv = tid >> 6;
    int ln = lane & 15, q = lane >> 4;
    int vb = blockIdx.x * 64 + wv * 16;

    const u16* Bhi = (const u16*)(ws + OFF_WOUTHI) + (size_t)(vb + ln) * 1024;
    const u16* Blo = (const u16*)(ws + OFF_WOUTLO) + (size_t)(vb + ln) * 1024;
    u64* partials = (u64*)(ws + OFF_PART);
    int* ctr = (int*)(ws + OFF_CTR);
    u16* XHi = (u16*)(ws + OFF_XHI);
    u16* XLo = (u16*)(ws + OFF_XLO);

    f32x4 acc[4];
#pragma unroll
    for (int i = 0; i < 4; i++) acc[i] = (f32x4){0.f, 0.f, 0.f, 0.f};
    plane_gemm_16n(hHi, hLo, Bhi, Blo, ln, q, acc);

    if (tid < 64) redLds[tid] = 0ull;
    __syncthreads();

    int v = vb + ln;
    float bo = bout[v];
#pragma unroll
    for (int mt = 0; mt < 4; mt++)
#pragma unroll
        for (int r = 0; r < 4; r++) {
            float lg = acc[mt][r] + bo;
            u64 key = ((u64)ord_of_float(lg) << 32)
                    | (u64)(0x7FFFFFFFu - (uint32_t)v);
#pragma unroll
            for (int m = 1; m < 16; m <<= 1) {   // reduce over ln (v within subtile)
                u64 o = shfl_xor_u64(key, m);
                if (o > key) key = o;
            }
            if (ln == 0) {
                int b = mt * 16 + q * 4 + r;
                atomicMax(&redLds[b], key);
            }
        }
    __syncthreads();
    if (tid < 64) partials[blockIdx.x * 64 + tid] = redLds[tid];
    __syncthreads();
    if (tid == 0) {
        __threadfence();
        int old = atomicAdd(&ctr[16], 1);
        isLast = (old == 499);
    }
    __syncthreads();
    if (isLast) {
        if (tid == 0) __threadfence();
        __syncthreads();
        if (tid < 64) redLds[tid] = 0ull;
        __syncthreads();
        {
            int b = tid & 63;
            u64 k = 0ull;
            for (int i = tid >> 6; i < 500; i += 4) {
                u64 p = partials[i * 64 + b];
                if (p > k) k = p;
            }
            atomicMax(&redLds[b], k);
        }
        __syncthreads();
        if (tid < 64) {
            int tk = (int)(0x7FFFFFFFu - (uint32_t)(redLds[tid] & 0xFFFFFFFFull));
            tokLds[tid] = tk;
            out[tid * T_ + t] = (float)tk;
        }
        __syncthreads();
        if (doX) {                           // build x(t+1) = emb[tok] planes
            for (int i = tid; i < B_ * H_; i += 256) {
                int b = i >> 10, kk = i & 1023;
                float vv = emb[(size_t)tokLds[b] * H_ + kk];
                split_bf16(vv, XHi + i, XLo + i);
            }
        }
        if (tid == 0) ctr[16] = 0;
    }
}

// ---------------- final h copy ----------------
__global__ __launch_bounds__(256) void k_copy_h(const float* __restrict__ h,
                                               float* __restrict__ out)
{
    int i = blockIdx.x * 256 + threadIdx.x;
    ((float4*)out)[i] = ((const float4*)h)[i];
}

// ---------------- launch ----------------
extern "C" void kernel_launch(void* const* d_in, const int* in_sizes, int n_in,
                              void* d_out, int out_size, void* d_ws, size_t ws_size,
                              hipStream_t stream)
{
    const float* latent = (const float*)d_in[0];
    const float* Wp     = (const float*)d_in[1];
    const float* bp     = (const float*)d_in[2];
    const float* emb    = (const float*)d_in[3];
    const float* Wih    = (const float*)d_in[4];
    const float* bih    = (const float*)d_in[5];
    const float* Whh    = (const float*)d_in[6];
    const float* bhh    = (const float*)d_in[7];
    const float* Wout   = (const float*)d_in[8];
    const float* bout   = (const float*)d_in[9];
    float* out = (float*)d_out;
    char* ws = (char*)d_ws;

    float* hb[2]  = {(float*)(ws + OFF_HB0), (float*)(ws + OFF_HB1)};
    u16* hHi[2]   = {(u16*)(ws + OFF_HHI0), (u16*)(ws + OFF_HHI1)};
    u16* hLo[2]   = {(u16*)(ws + OFF_HLO0), (u16*)(ws + OFF_HLO1)};
    u16* xHi      = (u16*)(ws + OFF_XHI);
    u16* xLo      = (u16*)(ws + OFF_XLO);

    k_split<<<4096, 256, 0, stream>>>(Wout, Wih, Whh, Wp, latent, emb, ws);
    k_init<<<16, 256, 0, stream>>>(bp, ws);

    for (int t = 0; t < T_; t++) {
        int p = t & 1;
        k_gates<<<32, 256, 0, stream>>>(bih, bhh, xHi, xLo,
                                        hHi[p], hLo[p], hb[p],
                                        hb[1 - p], hHi[1 - p], hLo[1 - p], ws);
        k_logits<<<500, 256, 0, stream>>>(hHi[1 - p], hLo[1 - p], bout, emb,
                                          out, t, t < T_ - 1 ? 1 : 0, ws);
    }
    k_copy_h<<<64, 256, 0, stream>>>(hb[0], out + B_ * T_);
}